// Round 6
// baseline (331.701 us; speedup 1.0000x reference)
//
#include <hip/hip_runtime.h>
#include <cmath>

// ---------------------------------------------------------------------------
// Causal MHA. B=4, T=2048, C=1024, NH=16, HD=64.
//   0) cast x -> bf16; transpose-cast w_qkv, w_out -> bf16 [N,K]
//   1) qkv_bf16 = xb @ wqkvT^T      (m97-style bf16 MFMA GEMM, bf16 out)
//   1b) Vt[b,h][hd][T] = transpose of V
//   2) flash attention (bf16 MFMA, fixed-max softmax, 128-row Q-tiles,
//      software-pipelined staging, l via ones-MFMA)  -> ctx bf16
//   3) out = ctxb @ woutT^T + b_out (bf16 MFMA GEMM, fp32 out)
// ---------------------------------------------------------------------------

typedef __bf16 bf16x4 __attribute__((ext_vector_type(4)));
typedef __bf16 bf16x8 __attribute__((ext_vector_type(8)));
typedef float  f32x4  __attribute__((ext_vector_type(4)));

__device__ __forceinline__ void gload_lds16(const __bf16* g, __bf16* l) {
    __builtin_amdgcn_global_load_lds(
        (const __attribute__((address_space(1))) void*)g,
        (__attribute__((address_space(3))) void*)l,
        16, 0, 0);
}

// ---- cast fp32 -> bf16, 4 elems/thread -------------------------------------
__global__ __launch_bounds__(256) void cast_bf16(const float* __restrict__ in,
                                                 __bf16* __restrict__ out, int n4) {
    int i = blockIdx.x * 256 + threadIdx.x;
    if (i >= n4) return;
    float4 f = *(const float4*)(in + (size_t)i * 4);
    bf16x4 o;
    o[0] = (__bf16)f.x; o[1] = (__bf16)f.y; o[2] = (__bf16)f.z; o[3] = (__bf16)f.w;
    *(bf16x4*)(out + (size_t)i * 4) = o;
}

// ---- transpose + cast: W[K,N] fp32 -> WT[N,K] bf16 -------------------------
__global__ __launch_bounds__(256) void transpose_cast(const float* __restrict__ W,
                                                      __bf16* __restrict__ WT,
                                                      int K, int N) {
    __shared__ float tile[32][33];
    const int n0 = blockIdx.x * 32, k0 = blockIdx.y * 32;
    const int tx = threadIdx.x & 31, ty = threadIdx.x >> 5;
    #pragma unroll
    for (int i = 0; i < 4; ++i)
        tile[ty + 8 * i][tx] = W[(size_t)(k0 + ty + 8 * i) * N + n0 + tx];
    __syncthreads();
    #pragma unroll
    for (int i = 0; i < 4; ++i)
        WT[(size_t)(n0 + ty + 8 * i) * K + k0 + tx] = (__bf16)tile[tx][ty + 8 * i];
}

// ---- V transpose: qkv V columns -> Vt[bh][hd=64][T=2048] -------------------
__global__ __launch_bounds__(256) void transpose_v(const __bf16* __restrict__ qkv,
                                                   __bf16* __restrict__ Vt) {
    constexpr int T = 2048, R3C = 3072;
    __shared__ __bf16 tile[64][72];
    const int bh = blockIdx.y;
    const int b  = bh >> 4, h = bh & 15;
    const int kt = blockIdx.x * 64;
    const int tid = threadIdx.x;
    #pragma unroll
    for (int i = 0; i < 2; ++i) {
        int idx = tid + 256 * i;
        int kr  = idx >> 3;
        int c8  = idx & 7;
        *(uint4*)&tile[kr][c8 * 8] =
            *(const uint4*)(qkv + (size_t)(b * T + kt + kr) * R3C + 2048 + h * 64 + c8 * 8);
    }
    __syncthreads();
    #pragma unroll
    for (int i = 0; i < 2; ++i) {
        int idx = tid + 256 * i;
        int d   = idx >> 3;
        int k8  = idx & 7;
        union { __bf16 v[8]; uint4 u; } t;
        #pragma unroll
        for (int j = 0; j < 8; ++j) t.v[j] = tile[k8 * 8 + j][d];
        *(uint4*)(Vt + ((size_t)bh * 64 + d) * T + kt + k8 * 8) = t.u;
    }
}

// ---------------------------------------------------------------------------
// m97-structure bf16 GEMM: C[M,N] = A[M,K] @ BT[N,K]^T (+bias).
// ---------------------------------------------------------------------------
template <typename OutT, bool BIAS>
__global__ __launch_bounds__(256) void gemm_bt(const __bf16* __restrict__ A,
                                               const __bf16* __restrict__ BT,
                                               OutT* __restrict__ Cc,
                                               const float* __restrict__ bias,
                                               int M, int N, int K) {
    __shared__ __bf16 As[128 * 32];
    __shared__ __bf16 Bs[128 * 32];

    const int tid  = threadIdx.x;
    const int lane = tid & 63;
    const int w    = tid >> 6;
    const int wr   = w >> 1, wc = w & 1;
    const int cc   = lane & 15, gg = lane >> 4;
    const int rowBase = blockIdx.y * 128;
    const int colBase = blockIdx.x * 128;

    f32x4 acc[4][4];
    #pragma unroll
    for (int i = 0; i < 4; ++i)
        #pragma unroll
        for (int j = 0; j < 4; ++j) acc[i][j] = f32x4{0.f, 0.f, 0.f, 0.f};

    for (int k0 = 0; k0 < K; k0 += 32) {
        __syncthreads();
        #pragma unroll
        for (int i = 0; i < 2; ++i) {
            int idx = tid + 256 * i;
            int r   = idx >> 2;
            int c4  = idx & 3;
            gload_lds16(A  + (size_t)(rowBase + r) * K + k0 + c4 * 8, &As[idx * 8]);
            gload_lds16(BT + (size_t)(colBase + r) * K + k0 + c4 * 8, &Bs[idx * 8]);
        }
        __syncthreads();

        bf16x8 af[4], bfr[4];
        #pragma unroll
        for (int i = 0; i < 4; ++i)
            af[i] = *(const bf16x8*)&As[(wr * 64 + i * 16 + cc) * 32 + gg * 8];
        #pragma unroll
        for (int j = 0; j < 4; ++j)
            bfr[j] = *(const bf16x8*)&Bs[(wc * 64 + j * 16 + cc) * 32 + gg * 8];
        #pragma unroll
        for (int i = 0; i < 4; ++i)
            #pragma unroll
            for (int j = 0; j < 4; ++j)
                acc[i][j] = __builtin_amdgcn_mfma_f32_16x16x32_bf16(af[i], bfr[j], acc[i][j], 0, 0, 0);
    }

    #pragma unroll
    for (int i = 0; i < 4; ++i)
        #pragma unroll
        for (int j = 0; j < 4; ++j) {
            const int col = colBase + wc * 64 + j * 16 + cc;
            #pragma unroll
            for (int r = 0; r < 4; ++r) {
                const int row = rowBase + wr * 64 + i * 16 + gg * 4 + r;
                float v = acc[i][j][r];
                if (BIAS) v += bias[col];
                Cc[(size_t)row * N + col] = (OutT)v;
            }
        }
}

// ---------------------------------------------------------------------------
// MFMA flash attention: 128-row Q-tile/block, wave owns 2 strips of 16 rows.
// Fixed-max softmax: p = exp2(s*0.125*log2e - 16*log2e).
// l accumulated by MFMA against an all-ones B fragment (no VALU adds).
// Staging software-pipelined: tile t+1 K/V global->VGPR issued before tile t
// compute; vmcnt drains at next iteration's ds_write (latency hidden).
// Grid (bh=64, qt=16), qt reversed so heaviest blocks dispatch first (LPT).
// ---------------------------------------------------------------------------
__global__ __launch_bounds__(256, 4) void flash_attn_mfma(const __bf16* __restrict__ qkv,
                                                          const __bf16* __restrict__ Vt,
                                                          __bf16* __restrict__ ctx) {
    constexpr int T = 2048, C = 1024, NH = 16, HD = 64;
    constexpr int R3C = 3 * C;
    constexpr float K1 = 0.125f * 1.44269504088896f;   // scale * log2e
    constexpr float K2 = -16.0f * 1.44269504088896f;   // -M0 * log2e

    const int tid  = threadIdx.x;
    const int lane = tid & 63;
    const int w    = tid >> 6;
    const int c    = lane & 15;
    const int g    = lane >> 4;

    const int bh    = blockIdx.x;              // 0..63
    const int qt    = 15 - (int)blockIdx.y;    // heavy-first
    const int b     = bh >> 4;
    const int h     = bh & 15;
    const int qbase = qt * 128;

    __shared__ __attribute__((aligned(16))) __bf16 Ks [64][72];
    __shared__ __attribute__((aligned(16))) __bf16 VsT[64][72];
    __shared__ __attribute__((aligned(16))) __bf16 Ps [4][32][72];

    // Q fragments for 2 strips (rows qbase + w*32 + st*16 + c)
    const __bf16* Qhead = qkv + (size_t)(b * T) * R3C + h * HD;
    bf16x8 Qa[2][2];
    #pragma unroll
    for (int st = 0; st < 2; ++st)
        #pragma unroll
        for (int ks = 0; ks < 2; ++ks)
            Qa[st][ks] = *(const bf16x8*)(Qhead +
                (size_t)(qbase + w * 32 + st * 16 + c) * R3C + ks * 32 + g * 8);

    f32x4 O0[4], O1[4], L0, L1;
    #pragma unroll
    for (int n = 0; n < 4; ++n) { O0[n] = f32x4{0.f,0.f,0.f,0.f}; O1[n] = f32x4{0.f,0.f,0.f,0.f}; }
    L0 = f32x4{0.f,0.f,0.f,0.f}; L1 = f32x4{0.f,0.f,0.f,0.f};

    bf16x8 ones;
    #pragma unroll
    for (int j = 0; j < 8; ++j) ones[j] = (__bf16)1.0f;

    const __bf16* Kb  = qkv + (size_t)(b * T) * R3C + C + h * HD;
    const __bf16* Vtb = Vt + (size_t)bh * 64 * T;

    const int srow0 = qbase + w * 32;
    const int srow1 = srow0 + 16;
    const int ktmax = qbase + 64;

    // staging indices (fixed per thread)
    const int krA = tid >> 3,        c8A = tid & 7;          // idx = tid
    const int krB = (tid + 256) >> 3, c8B = tid & 7;         // idx = tid+256

    // prologue: load tile 0 into registers
    uint4 kreg0 = *(const uint4*)(Kb + (size_t)krA * R3C + c8A * 8);
    uint4 kreg1 = *(const uint4*)(Kb + (size_t)krB * R3C + c8B * 8);
    uint4 vreg0 = *(const uint4*)(Vtb + (size_t)krA * T + c8A * 8);
    uint4 vreg1 = *(const uint4*)(Vtb + (size_t)krB * T + c8B * 8);

    for (int kt = 0; kt <= ktmax; kt += 64) {
        __syncthreads();                       // previous tile's LDS reads done
        *(uint4*)&Ks [krA][c8A * 8] = kreg0;   // waits vmcnt here (hidden)
        *(uint4*)&Ks [krB][c8B * 8] = kreg1;
        *(uint4*)&VsT[krA][c8A * 8] = vreg0;
        *(uint4*)&VsT[krB][c8B * 8] = vreg1;
        __syncthreads();                       // staging visible

        // prefetch tile t+1 (no wait until next iteration's ds_write)
        if (kt + 64 <= ktmax) {
            const __bf16* Kn = Kb + (size_t)(kt + 64) * R3C;
            kreg0 = *(const uint4*)(Kn + (size_t)krA * R3C + c8A * 8);
            kreg1 = *(const uint4*)(Kn + (size_t)krB * R3C + c8B * 8);
            vreg0 = *(const uint4*)(Vtb + (size_t)krA * T + kt + 64 + c8A * 8);
            vreg1 = *(const uint4*)(Vtb + (size_t)krB * T + kt + 64 + c8B * 8);
        }

        // S = Q @ K^T for both strips, sharing each K fragment
        f32x4 S0[4], S1[4];
        #pragma unroll
        for (int s = 0; s < 4; ++s) { S0[s] = f32x4{0.f,0.f,0.f,0.f}; S1[s] = f32x4{0.f,0.f,0.f,0.f}; }
        #pragma unroll
        for (int ks = 0; ks < 2; ++ks)
            #pragma unroll
            for (int sub = 0; sub < 4; ++sub) {
                bf16x8 kb = *(const bf16x8*)&Ks[sub * 16 + c][ks * 32 + g * 8];
                S0[sub] = __builtin_amdgcn_mfma_f32_16x16x32_bf16(Qa[0][ks], kb, S0[sub], 0, 0, 0);
                S1[sub] = __builtin_amdgcn_mfma_f32_16x16x32_bf16(Qa[1][ks], kb, S1[sub], 0, 0, 0);
            }
        // causal mask (wave-uniform tests; masked lanes -> p = 0)
        if (kt + 63 > srow0) {
            #pragma unroll
            for (int sub = 0; sub < 4; ++sub) {
                int key = kt + sub * 16 + c;
                #pragma unroll
                for (int r = 0; r < 4; ++r)
                    if (key > srow0 + g * 4 + r) S0[sub][r] = -1e30f;
            }
        }
        if (kt + 63 > srow1) {
            #pragma unroll
            for (int sub = 0; sub < 4; ++sub) {
                int key = kt + sub * 16 + c;
                #pragma unroll
                for (int r = 0; r < 4; ++r)
                    if (key > srow1 + g * 4 + r) S1[sub][r] = -1e30f;
            }
        }
        // fixed-max softmax; pack P into per-wave LDS (C-layout -> A-layout)
        #pragma unroll
        for (int sub = 0; sub < 4; ++sub)
            #pragma unroll
            for (int r = 0; r < 4; ++r) {
                float p0 = exp2f(fmaf(S0[sub][r], K1, K2));
                float p1 = exp2f(fmaf(S1[sub][r], K1, K2));
                Ps[w][g * 4 + r]     [sub * 16 + c] = (__bf16)p0;
                Ps[w][16 + g * 4 + r][sub * 16 + c] = (__bf16)p1;
            }

        // O += P @ V ; L += P @ 1 (ones fragment -> row sums, no VALU adds)
        #pragma unroll
        for (int ks = 0; ks < 2; ++ks) {
            bf16x8 pa0 = *(const bf16x8*)&Ps[w][c]     [ks * 32 + g * 8];
            bf16x8 pa1 = *(const bf16x8*)&Ps[w][16 + c][ks * 32 + g * 8];
            #pragma unroll
            for (int n = 0; n < 4; ++n) {
                bf16x8 vb = *(const bf16x8*)&VsT[n * 16 + c][ks * 32 + g * 8];
                O0[n] = __builtin_amdgcn_mfma_f32_16x16x32_bf16(pa0, vb, O0[n], 0, 0, 0);
                O1[n] = __builtin_amdgcn_mfma_f32_16x16x32_bf16(pa1, vb, O1[n], 0, 0, 0);
            }
            L0 = __builtin_amdgcn_mfma_f32_16x16x32_bf16(pa0, ones, L0, 0, 0, 0);
            L1 = __builtin_amdgcn_mfma_f32_16x16x32_bf16(pa1, ones, L1, 0, 0, 0);
        }
    }

    float i0[4], i1[4];
    #pragma unroll
    for (int r = 0; r < 4; ++r) { i0[r] = 1.f / L0[r]; i1[r] = 1.f / L1[r]; }
    #pragma unroll
    for (int n = 0; n < 4; ++n)
        #pragma unroll
        for (int r = 0; r < 4; ++r) {
            size_t row0 = (size_t)(b * T + srow0 + g * 4 + r);
            size_t row1 = (size_t)(b * T + srow1 + g * 4 + r);
            ctx[row0 * C + h * HD + n * 16 + c] = (__bf16)(O0[n][r] * i0[r]);
            ctx[row1 * C + h * HD + n * 16 + c] = (__bf16)(O1[n][r] * i1[r]);
        }
}

extern "C" void kernel_launch(void* const* d_in, const int* in_sizes, int n_in,
                              void* d_out, int out_size, void* d_ws, size_t ws_size,
                              hipStream_t stream) {
    constexpr int B = 4, T = 2048, C = 1024;
    constexpr int M = B * T;          // 8192

    const float* x     = (const float*)d_in[0];
    const float* w_qkv = (const float*)d_in[1];
    const float* w_out = (const float*)d_in[2];
    const float* b_out = (const float*)d_in[3];
    float* out = (float*)d_out;

    char* ws = (char*)d_ws;
    __bf16* xb     = (__bf16*)(ws);                      // 16 MB
    __bf16* wqkvT  = (__bf16*)(ws + (16ull << 20));      //  6 MB
    __bf16* woutT  = (__bf16*)(ws + (22ull << 20));      //  2 MB
    __bf16* qkvb   = (__bf16*)(ws + (24ull << 20));      // 48 MB
    __bf16* ctxb   = (__bf16*)(ws + (72ull << 20));      // 16 MB
    __bf16* Vt     = (__bf16*)(ws + (88ull << 20));      // 16 MB

    // 0) casts / transposes
    cast_bf16<<<(M * C / 4 + 255) / 256, 256, 0, stream>>>(x, xb, M * C / 4);
    transpose_cast<<<dim3(3 * C / 32, C / 32), 256, 0, stream>>>(w_qkv, wqkvT, C, 3 * C);
    transpose_cast<<<dim3(C / 32, C / 32), 256, 0, stream>>>(w_out, woutT, C, C);

    // 1) qkv = xb @ wqkvT^T  (bf16 out)
    gemm_bt<__bf16, false><<<dim3(3 * C / 128, M / 128), 256, 0, stream>>>(
        xb, wqkvT, qkvb, nullptr, M, 3 * C, C);

    // 1b) V transpose
    transpose_v<<<dim3(T / 64, B * 16), 256, 0, stream>>>(qkvb, Vt);

    // 2) MFMA flash attention -> ctxb  (128-row Q-tiles, heavy-first)
    flash_attn_mfma<<<dim3(B * 16, T / 128), 256, 0, stream>>>(qkvb, Vt, ctxb);

    // 3) out = ctxb @ woutT^T + b_out (fp32 out)
    gemm_bt<float, true><<<dim3(C / 128, M / 128), 256, 0, stream>>>(
        ctxb, woutT, out, b_out, M, C, C);
}

// Round 7
// 310.491 us; speedup vs baseline: 1.0683x; 1.0683x over previous
//
#include <hip/hip_runtime.h>
#include <cmath>

// ---------------------------------------------------------------------------
// Causal MHA. B=4, T=2048, C=1024, NH=16, HD=64.
//   0) cast x -> bf16; transpose-cast w_qkv, w_out -> bf16 [N,K]
//   1) qkv_bf16 = xb @ wqkvT^T      (m97-style bf16 MFMA GEMM, bf16 out)
//   1b) Vt[b,h][hd][T] = transpose of V
//   2) flash attention (bf16 MFMA, fixed-max softmax, 128-row Q-tiles,
//      synchronous staging [r6 reg-prefetch spilled], l via ones-MFMA)
//   3) out = ctxb @ woutT^T + b_out (bf16 MFMA GEMM, fp32 out)
// NOTE (r6 post-mortem): register prefetch + __launch_bounds__(256,4) caused
// scratch spill (WRITE_SIZE 16->107MB). Do NOT cap VGPRs or hold long-lived
// prefetch registers across the MFMA section in this kernel.
// ---------------------------------------------------------------------------

typedef __bf16 bf16x4 __attribute__((ext_vector_type(4)));
typedef __bf16 bf16x8 __attribute__((ext_vector_type(8)));
typedef float  f32x4  __attribute__((ext_vector_type(4)));

__device__ __forceinline__ void gload_lds16(const __bf16* g, __bf16* l) {
    __builtin_amdgcn_global_load_lds(
        (const __attribute__((address_space(1))) void*)g,
        (__attribute__((address_space(3))) void*)l,
        16, 0, 0);
}

// ---- cast fp32 -> bf16, 4 elems/thread -------------------------------------
__global__ __launch_bounds__(256) void cast_bf16(const float* __restrict__ in,
                                                 __bf16* __restrict__ out, int n4) {
    int i = blockIdx.x * 256 + threadIdx.x;
    if (i >= n4) return;
    float4 f = *(const float4*)(in + (size_t)i * 4);
    bf16x4 o;
    o[0] = (__bf16)f.x; o[1] = (__bf16)f.y; o[2] = (__bf16)f.z; o[3] = (__bf16)f.w;
    *(bf16x4*)(out + (size_t)i * 4) = o;
}

// ---- transpose + cast: W[K,N] fp32 -> WT[N,K] bf16 -------------------------
__global__ __launch_bounds__(256) void transpose_cast(const float* __restrict__ W,
                                                      __bf16* __restrict__ WT,
                                                      int K, int N) {
    __shared__ float tile[32][33];
    const int n0 = blockIdx.x * 32, k0 = blockIdx.y * 32;
    const int tx = threadIdx.x & 31, ty = threadIdx.x >> 5;
    #pragma unroll
    for (int i = 0; i < 4; ++i)
        tile[ty + 8 * i][tx] = W[(size_t)(k0 + ty + 8 * i) * N + n0 + tx];
    __syncthreads();
    #pragma unroll
    for (int i = 0; i < 4; ++i)
        WT[(size_t)(n0 + ty + 8 * i) * K + k0 + tx] = (__bf16)tile[tx][ty + 8 * i];
}

// ---- V transpose: qkv V columns -> Vt[bh][hd=64][T=2048] -------------------
__global__ __launch_bounds__(256) void transpose_v(const __bf16* __restrict__ qkv,
                                                   __bf16* __restrict__ Vt) {
    constexpr int T = 2048, R3C = 3072;
    __shared__ __bf16 tile[64][72];
    const int bh = blockIdx.y;
    const int b  = bh >> 4, h = bh & 15;
    const int kt = blockIdx.x * 64;
    const int tid = threadIdx.x;
    #pragma unroll
    for (int i = 0; i < 2; ++i) {
        int idx = tid + 256 * i;
        int kr  = idx >> 3;
        int c8  = idx & 7;
        *(uint4*)&tile[kr][c8 * 8] =
            *(const uint4*)(qkv + (size_t)(b * T + kt + kr) * R3C + 2048 + h * 64 + c8 * 8);
    }
    __syncthreads();
    #pragma unroll
    for (int i = 0; i < 2; ++i) {
        int idx = tid + 256 * i;
        int d   = idx >> 3;
        int k8  = idx & 7;
        union { __bf16 v[8]; uint4 u; } t;
        #pragma unroll
        for (int j = 0; j < 8; ++j) t.v[j] = tile[k8 * 8 + j][d];
        *(uint4*)(Vt + ((size_t)bh * 64 + d) * T + kt + k8 * 8) = t.u;
    }
}

// ---------------------------------------------------------------------------
// m97-structure bf16 GEMM: C[M,N] = A[M,K] @ BT[N,K]^T (+bias).
// ---------------------------------------------------------------------------
template <typename OutT, bool BIAS>
__global__ __launch_bounds__(256) void gemm_bt(const __bf16* __restrict__ A,
                                               const __bf16* __restrict__ BT,
                                               OutT* __restrict__ Cc,
                                               const float* __restrict__ bias,
                                               int M, int N, int K) {
    __shared__ __bf16 As[128 * 32];
    __shared__ __bf16 Bs[128 * 32];

    const int tid  = threadIdx.x;
    const int lane = tid & 63;
    const int w    = tid >> 6;
    const int wr   = w >> 1, wc = w & 1;
    const int cc   = lane & 15, gg = lane >> 4;
    const int rowBase = blockIdx.y * 128;
    const int colBase = blockIdx.x * 128;

    f32x4 acc[4][4];
    #pragma unroll
    for (int i = 0; i < 4; ++i)
        #pragma unroll
        for (int j = 0; j < 4; ++j) acc[i][j] = f32x4{0.f, 0.f, 0.f, 0.f};

    for (int k0 = 0; k0 < K; k0 += 32) {
        __syncthreads();
        #pragma unroll
        for (int i = 0; i < 2; ++i) {
            int idx = tid + 256 * i;
            int r   = idx >> 2;
            int c4  = idx & 3;
            gload_lds16(A  + (size_t)(rowBase + r) * K + k0 + c4 * 8, &As[idx * 8]);
            gload_lds16(BT + (size_t)(colBase + r) * K + k0 + c4 * 8, &Bs[idx * 8]);
        }
        __syncthreads();

        bf16x8 af[4], bfr[4];
        #pragma unroll
        for (int i = 0; i < 4; ++i)
            af[i] = *(const bf16x8*)&As[(wr * 64 + i * 16 + cc) * 32 + gg * 8];
        #pragma unroll
        for (int j = 0; j < 4; ++j)
            bfr[j] = *(const bf16x8*)&Bs[(wc * 64 + j * 16 + cc) * 32 + gg * 8];
        #pragma unroll
        for (int i = 0; i < 4; ++i)
            #pragma unroll
            for (int j = 0; j < 4; ++j)
                acc[i][j] = __builtin_amdgcn_mfma_f32_16x16x32_bf16(af[i], bfr[j], acc[i][j], 0, 0, 0);
    }

    #pragma unroll
    for (int i = 0; i < 4; ++i)
        #pragma unroll
        for (int j = 0; j < 4; ++j) {
            const int col = colBase + wc * 64 + j * 16 + cc;
            #pragma unroll
            for (int r = 0; r < 4; ++r) {
                const int row = rowBase + wr * 64 + i * 16 + gg * 4 + r;
                float v = acc[i][j][r];
                if (BIAS) v += bias[col];
                Cc[(size_t)row * N + col] = (OutT)v;
            }
        }
}

// ---------------------------------------------------------------------------
// MFMA flash attention: 128-row Q-tile/block, wave owns 2 strips of 16 rows.
// Fixed-max softmax: p = exp2(s*0.125*log2e - 16*log2e).
// l accumulated by MFMA against an all-ones B fragment (no VALU adds,
// no epilogue shuffle-reduce). Synchronous LDS staging (r5 structure).
// Grid (bh=64, qt=16), qt reversed so heaviest blocks dispatch first (LPT).
// ---------------------------------------------------------------------------
__global__ __launch_bounds__(256) void flash_attn_mfma(const __bf16* __restrict__ qkv,
                                                       const __bf16* __restrict__ Vt,
                                                       __bf16* __restrict__ ctx) {
    constexpr int T = 2048, C = 1024, NH = 16, HD = 64;
    constexpr int R3C = 3 * C;
    constexpr float K1 = 0.125f * 1.44269504088896f;   // scale * log2e
    constexpr float K2 = -16.0f * 1.44269504088896f;   // -M0 * log2e

    const int tid  = threadIdx.x;
    const int lane = tid & 63;
    const int w    = tid >> 6;
    const int c    = lane & 15;
    const int g    = lane >> 4;

    const int bh    = blockIdx.x;              // 0..63
    const int qt    = 15 - (int)blockIdx.y;    // heavy-first
    const int b     = bh >> 4;
    const int h     = bh & 15;
    const int qbase = qt * 128;

    __shared__ __attribute__((aligned(16))) __bf16 Ks [64][72];
    __shared__ __attribute__((aligned(16))) __bf16 VsT[64][72];
    __shared__ __attribute__((aligned(16))) __bf16 Ps [4][32][72];

    // Q fragments for 2 strips (rows qbase + w*32 + st*16 + c)
    const __bf16* Qhead = qkv + (size_t)(b * T) * R3C + h * HD;
    bf16x8 Qa[2][2];
    #pragma unroll
    for (int st = 0; st < 2; ++st)
        #pragma unroll
        for (int ks = 0; ks < 2; ++ks)
            Qa[st][ks] = *(const bf16x8*)(Qhead +
                (size_t)(qbase + w * 32 + st * 16 + c) * R3C + ks * 32 + g * 8);

    f32x4 O0[4], O1[4], L0, L1;
    #pragma unroll
    for (int n = 0; n < 4; ++n) { O0[n] = f32x4{0.f,0.f,0.f,0.f}; O1[n] = f32x4{0.f,0.f,0.f,0.f}; }
    L0 = f32x4{0.f,0.f,0.f,0.f}; L1 = f32x4{0.f,0.f,0.f,0.f};

    bf16x8 ones;
    #pragma unroll
    for (int j = 0; j < 8; ++j) ones[j] = (__bf16)1.0f;

    const __bf16* Kb  = qkv + (size_t)(b * T) * R3C + C + h * HD;
    const __bf16* Vtb = Vt + (size_t)bh * 64 * T;

    const int srow0 = qbase + w * 32;
    const int srow1 = srow0 + 16;
    const int ktmax = qbase + 64;

    for (int kt = 0; kt <= ktmax; kt += 64) {
        __syncthreads();
        // stage K tile: Ks[key][hd]
        #pragma unroll
        for (int i = 0; i < 2; ++i) {
            int idx = tid + 256 * i;
            int kr  = idx >> 3;
            int c8  = idx & 7;
            *(uint4*)&Ks[kr][c8 * 8] = *(const uint4*)(Kb + (size_t)(kt + kr) * R3C + c8 * 8);
        }
        // stage V^T tile: VsT[hd][key]
        #pragma unroll
        for (int i = 0; i < 2; ++i) {
            int idx = tid + 256 * i;
            int d   = idx >> 3;
            int k8  = idx & 7;
            *(uint4*)&VsT[d][k8 * 8] = *(const uint4*)(Vtb + (size_t)d * T + kt + k8 * 8);
        }
        __syncthreads();

        // S = Q @ K^T for both strips, sharing each K fragment
        f32x4 S0[4], S1[4];
        #pragma unroll
        for (int s = 0; s < 4; ++s) { S0[s] = f32x4{0.f,0.f,0.f,0.f}; S1[s] = f32x4{0.f,0.f,0.f,0.f}; }
        #pragma unroll
        for (int ks = 0; ks < 2; ++ks)
            #pragma unroll
            for (int sub = 0; sub < 4; ++sub) {
                bf16x8 kb = *(const bf16x8*)&Ks[sub * 16 + c][ks * 32 + g * 8];
                S0[sub] = __builtin_amdgcn_mfma_f32_16x16x32_bf16(Qa[0][ks], kb, S0[sub], 0, 0, 0);
                S1[sub] = __builtin_amdgcn_mfma_f32_16x16x32_bf16(Qa[1][ks], kb, S1[sub], 0, 0, 0);
            }
        // causal mask (wave-uniform tests; masked lanes -> p = 0)
        if (kt + 63 > srow0) {
            #pragma unroll
            for (int sub = 0; sub < 4; ++sub) {
                int key = kt + sub * 16 + c;
                #pragma unroll
                for (int r = 0; r < 4; ++r)
                    if (key > srow0 + g * 4 + r) S0[sub][r] = -1e30f;
            }
        }
        if (kt + 63 > srow1) {
            #pragma unroll
            for (int sub = 0; sub < 4; ++sub) {
                int key = kt + sub * 16 + c;
                #pragma unroll
                for (int r = 0; r < 4; ++r)
                    if (key > srow1 + g * 4 + r) S1[sub][r] = -1e30f;
            }
        }
        // fixed-max softmax; pack P into per-wave LDS (C-layout -> A-layout)
        #pragma unroll
        for (int sub = 0; sub < 4; ++sub)
            #pragma unroll
            for (int r = 0; r < 4; ++r) {
                float p0 = exp2f(fmaf(S0[sub][r], K1, K2));
                float p1 = exp2f(fmaf(S1[sub][r], K1, K2));
                Ps[w][g * 4 + r]     [sub * 16 + c] = (__bf16)p0;
                Ps[w][16 + g * 4 + r][sub * 16 + c] = (__bf16)p1;
            }

        // O += P @ V ; L += P @ 1 (row sums via idle MFMA pipe)
        #pragma unroll
        for (int ks = 0; ks < 2; ++ks) {
            bf16x8 pa0 = *(const bf16x8*)&Ps[w][c]     [ks * 32 + g * 8];
            bf16x8 pa1 = *(const bf16x8*)&Ps[w][16 + c][ks * 32 + g * 8];
            #pragma unroll
            for (int n = 0; n < 4; ++n) {
                bf16x8 vb = *(const bf16x8*)&VsT[n * 16 + c][ks * 32 + g * 8];
                O0[n] = __builtin_amdgcn_mfma_f32_16x16x32_bf16(pa0, vb, O0[n], 0, 0, 0);
                O1[n] = __builtin_amdgcn_mfma_f32_16x16x32_bf16(pa1, vb, O1[n], 0, 0, 0);
            }
            L0 = __builtin_amdgcn_mfma_f32_16x16x32_bf16(pa0, ones, L0, 0, 0, 0);
            L1 = __builtin_amdgcn_mfma_f32_16x16x32_bf16(pa1, ones, L1, 0, 0, 0);
        }
    }

    float i0[4], i1[4];
    #pragma unroll
    for (int r = 0; r < 4; ++r) { i0[r] = 1.f / L0[r]; i1[r] = 1.f / L1[r]; }
    #pragma unroll
    for (int n = 0; n < 4; ++n)
        #pragma unroll
        for (int r = 0; r < 4; ++r) {
            size_t row0 = (size_t)(b * T + srow0 + g * 4 + r);
            size_t row1 = (size_t)(b * T + srow1 + g * 4 + r);
            ctx[row0 * C + h * HD + n * 16 + c] = (__bf16)(O0[n][r] * i0[r]);
            ctx[row1 * C + h * HD + n * 16 + c] = (__bf16)(O1[n][r] * i1[r]);
        }
}

extern "C" void kernel_launch(void* const* d_in, const int* in_sizes, int n_in,
                              void* d_out, int out_size, void* d_ws, size_t ws_size,
                              hipStream_t stream) {
    constexpr int B = 4, T = 2048, C = 1024;
    constexpr int M = B * T;          // 8192

    const float* x     = (const float*)d_in[0];
    const float* w_qkv = (const float*)d_in[1];
    const float* w_out = (const float*)d_in[2];
    const float* b_out = (const float*)d_in[3];
    float* out = (float*)d_out;

    char* ws = (char*)d_ws;
    __bf16* xb     = (__bf16*)(ws);                      // 16 MB
    __bf16* wqkvT  = (__bf16*)(ws + (16ull << 20));      //  6 MB
    __bf16* woutT  = (__bf16*)(ws + (22ull << 20));      //  2 MB
    __bf16* qkvb   = (__bf16*)(ws + (24ull << 20));      // 48 MB
    __bf16* ctxb   = (__bf16*)(ws + (72ull << 20));      // 16 MB
    __bf16* Vt     = (__bf16*)(ws + (88ull << 20));      // 16 MB

    // 0) casts / transposes
    cast_bf16<<<(M * C / 4 + 255) / 256, 256, 0, stream>>>(x, xb, M * C / 4);
    transpose_cast<<<dim3(3 * C / 32, C / 32), 256, 0, stream>>>(w_qkv, wqkvT, C, 3 * C);
    transpose_cast<<<dim3(C / 32, C / 32), 256, 0, stream>>>(w_out, woutT, C, C);

    // 1) qkv = xb @ wqkvT^T  (bf16 out)
    gemm_bt<__bf16, false><<<dim3(3 * C / 128, M / 128), 256, 0, stream>>>(
        xb, wqkvT, qkvb, nullptr, M, 3 * C, C);

    // 1b) V transpose
    transpose_v<<<dim3(T / 64, B * 16), 256, 0, stream>>>(qkvb, Vt);

    // 2) MFMA flash attention -> ctxb  (128-row Q-tiles, heavy-first)
    flash_attn_mfma<<<dim3(B * 16, T / 128), 256, 0, stream>>>(qkvb, Vt, ctxb);

    // 3) out = ctxb @ woutT^T + b_out (fp32 out)
    gemm_bt<float, true><<<dim3(C / 128, M / 128), 256, 0, stream>>>(
        ctxb, woutT, out, b_out, M, C, C);
}

// Round 8
// 289.837 us; speedup vs baseline: 1.1444x; 1.0713x over previous
//
#include <hip/hip_runtime.h>
#include <cmath>

// ---------------------------------------------------------------------------
// Causal MHA. B=4, T=2048, C=1024, NH=16, HD=64.
//   0) cast x -> bf16; transpose-cast w_qkv, w_out -> bf16 [N,K]
//   1) qkv_bf16 = xb @ wqkvT^T      (m97-style bf16 MFMA GEMM, bf16 out)
//   1b) Vt[b,h][hd][T] = transpose of V
//   2) flash attention: 32x32x16 MFMA, S^T/O^T orientation (b64 P-writes,
//      half the K/V frag reads), fixed-max softmax  -> ctx bf16
//   3) out = ctxb @ woutT^T + b_out (bf16 MFMA GEMM, fp32 out)
// NOTE (r6 post-mortem): register prefetch + __launch_bounds__(256,4) caused
// scratch spill (WRITE_SIZE 16->107MB). Do NOT cap VGPRs or hold long-lived
// prefetch registers across the MFMA section in the attention kernel.
// ---------------------------------------------------------------------------

typedef __bf16 bf16x4 __attribute__((ext_vector_type(4)));
typedef __bf16 bf16x8 __attribute__((ext_vector_type(8)));
typedef float  f32x4  __attribute__((ext_vector_type(4)));
typedef float  f32x16 __attribute__((ext_vector_type(16)));

__device__ __forceinline__ void gload_lds16(const __bf16* g, __bf16* l) {
    __builtin_amdgcn_global_load_lds(
        (const __attribute__((address_space(1))) void*)g,
        (__attribute__((address_space(3))) void*)l,
        16, 0, 0);
}

// ---- cast fp32 -> bf16, 4 elems/thread -------------------------------------
__global__ __launch_bounds__(256) void cast_bf16(const float* __restrict__ in,
                                                 __bf16* __restrict__ out, int n4) {
    int i = blockIdx.x * 256 + threadIdx.x;
    if (i >= n4) return;
    float4 f = *(const float4*)(in + (size_t)i * 4);
    bf16x4 o;
    o[0] = (__bf16)f.x; o[1] = (__bf16)f.y; o[2] = (__bf16)f.z; o[3] = (__bf16)f.w;
    *(bf16x4*)(out + (size_t)i * 4) = o;
}

// ---- transpose + cast: W[K,N] fp32 -> WT[N,K] bf16 -------------------------
__global__ __launch_bounds__(256) void transpose_cast(const float* __restrict__ W,
                                                      __bf16* __restrict__ WT,
                                                      int K, int N) {
    __shared__ float tile[32][33];
    const int n0 = blockIdx.x * 32, k0 = blockIdx.y * 32;
    const int tx = threadIdx.x & 31, ty = threadIdx.x >> 5;
    #pragma unroll
    for (int i = 0; i < 4; ++i)
        tile[ty + 8 * i][tx] = W[(size_t)(k0 + ty + 8 * i) * N + n0 + tx];
    __syncthreads();
    #pragma unroll
    for (int i = 0; i < 4; ++i)
        WT[(size_t)(n0 + ty + 8 * i) * K + k0 + tx] = (__bf16)tile[tx][ty + 8 * i];
}

// ---- V transpose: qkv V columns -> Vt[bh][hd=64][T=2048] -------------------
__global__ __launch_bounds__(256) void transpose_v(const __bf16* __restrict__ qkv,
                                                   __bf16* __restrict__ Vt) {
    constexpr int T = 2048, R3C = 3072;
    __shared__ __bf16 tile[64][72];
    const int bh = blockIdx.y;
    const int b  = bh >> 4, h = bh & 15;
    const int kt = blockIdx.x * 64;
    const int tid = threadIdx.x;
    #pragma unroll
    for (int i = 0; i < 2; ++i) {
        int idx = tid + 256 * i;
        int kr  = idx >> 3;
        int c8  = idx & 7;
        *(uint4*)&tile[kr][c8 * 8] =
            *(const uint4*)(qkv + (size_t)(b * T + kt + kr) * R3C + 2048 + h * 64 + c8 * 8);
    }
    __syncthreads();
    #pragma unroll
    for (int i = 0; i < 2; ++i) {
        int idx = tid + 256 * i;
        int d   = idx >> 3;
        int k8  = idx & 7;
        union { __bf16 v[8]; uint4 u; } t;
        #pragma unroll
        for (int j = 0; j < 8; ++j) t.v[j] = tile[k8 * 8 + j][d];
        *(uint4*)(Vt + ((size_t)bh * 64 + d) * T + kt + k8 * 8) = t.u;
    }
}

// ---------------------------------------------------------------------------
// m97-structure bf16 GEMM: C[M,N] = A[M,K] @ BT[N,K]^T (+bias).
// ---------------------------------------------------------------------------
template <typename OutT, bool BIAS>
__global__ __launch_bounds__(256) void gemm_bt(const __bf16* __restrict__ A,
                                               const __bf16* __restrict__ BT,
                                               OutT* __restrict__ Cc,
                                               const float* __restrict__ bias,
                                               int M, int N, int K) {
    __shared__ __bf16 As[128 * 32];
    __shared__ __bf16 Bs[128 * 32];

    const int tid  = threadIdx.x;
    const int lane = tid & 63;
    const int w    = tid >> 6;
    const int wr   = w >> 1, wc = w & 1;
    const int cc   = lane & 15, gg = lane >> 4;
    const int rowBase = blockIdx.y * 128;
    const int colBase = blockIdx.x * 128;

    f32x4 acc[4][4];
    #pragma unroll
    for (int i = 0; i < 4; ++i)
        #pragma unroll
        for (int j = 0; j < 4; ++j) acc[i][j] = f32x4{0.f, 0.f, 0.f, 0.f};

    for (int k0 = 0; k0 < K; k0 += 32) {
        __syncthreads();
        #pragma unroll
        for (int i = 0; i < 2; ++i) {
            int idx = tid + 256 * i;
            int r   = idx >> 2;
            int c4  = idx & 3;
            gload_lds16(A  + (size_t)(rowBase + r) * K + k0 + c4 * 8, &As[idx * 8]);
            gload_lds16(BT + (size_t)(colBase + r) * K + k0 + c4 * 8, &Bs[idx * 8]);
        }
        __syncthreads();

        bf16x8 af[4], bfr[4];
        #pragma unroll
        for (int i = 0; i < 4; ++i)
            af[i] = *(const bf16x8*)&As[(wr * 64 + i * 16 + cc) * 32 + gg * 8];
        #pragma unroll
        for (int j = 0; j < 4; ++j)
            bfr[j] = *(const bf16x8*)&Bs[(wc * 64 + j * 16 + cc) * 32 + gg * 8];
        #pragma unroll
        for (int i = 0; i < 4; ++i)
            #pragma unroll
            for (int j = 0; j < 4; ++j)
                acc[i][j] = __builtin_amdgcn_mfma_f32_16x16x32_bf16(af[i], bfr[j], acc[i][j], 0, 0, 0);
    }

    #pragma unroll
    for (int i = 0; i < 4; ++i)
        #pragma unroll
        for (int j = 0; j < 4; ++j) {
            const int col = colBase + wc * 64 + j * 16 + cc;
            #pragma unroll
            for (int r = 0; r < 4; ++r) {
                const int row = rowBase + wr * 64 + i * 16 + gg * 4 + r;
                float v = acc[i][j][r];
                if (BIAS) v += bias[col];
                Cc[(size_t)row * N + col] = (OutT)v;
            }
        }
}

// ---------------------------------------------------------------------------
// MFMA flash attention v3: 32x32x16, transposed orientation.
// Block = 4 waves; wave owns 32 q-rows (block tile = 128 q-rows).
// S^T = mfma(A=K_frag, B=Q_frag)  -> C-layout: col = q = lane&31,
//       row = key = (r&3) + 8*(r>>2) + 4*(lane>>5)   [guide m74/m101]
// Each lane holds 4-consecutive-key runs of ITS OWN q-row -> P-writes are
// packed ds_write_b64 into Ps[q][key]; PV reads Ps rows as B-frags.
// O^T = mfma(A=V^T_frag (from VsT), B=P_frag) -> lane-local q, packed stores.
// Fixed-max softmax p = exp2(s*0.125*log2e - 16*log2e); L per-lane + one
// shfl_xor(32). Heavy-first (LPT) dispatch.
// ---------------------------------------------------------------------------
__global__ __launch_bounds__(256) void flash_attn_mfma(const __bf16* __restrict__ qkv,
                                                       const __bf16* __restrict__ Vt,
                                                       __bf16* __restrict__ ctx) {
    constexpr int T = 2048, C = 1024, NH = 16, HD = 64;
    constexpr int R3C = 3 * C;
    constexpr float K1 = 0.125f * 1.44269504088896f;   // scale * log2e
    constexpr float K2 = -16.0f * 1.44269504088896f;   // -M0 * log2e

    const int tid  = threadIdx.x;
    const int lane = tid & 63;
    const int w    = tid >> 6;
    const int q5   = lane & 31;                // q-col within wave tile
    const int half = lane >> 5;                // 0/1

    const int bh    = blockIdx.x;              // 0..63
    const int qt    = 15 - (int)blockIdx.y;    // heavy-first
    const int b     = bh >> 4;
    const int h     = bh & 15;
    const int qbase = qt * 128;
    const int srow  = qbase + w * 32;          // this wave's first q-row

    __shared__ __attribute__((aligned(16))) __bf16 Ks [64][72];   // [key][hd]
    __shared__ __attribute__((aligned(16))) __bf16 VsT[64][72];   // [hd][key]
    __shared__ __attribute__((aligned(16))) __bf16 Ps [4][32][72];// per-wave P[q][key]

    // Q as B-fragments: B[n=q5][k=ks*16+half*8+j], loaded once.
    const __bf16* Qrow = qkv + (size_t)(b * T + srow + q5) * R3C + h * HD;
    bf16x8 Qb[4];
    #pragma unroll
    for (int ks = 0; ks < 4; ++ks)
        Qb[ks] = *(const bf16x8*)(Qrow + ks * 16 + half * 8);

    f32x16 O[2];
    #pragma unroll
    for (int mb = 0; mb < 2; ++mb)
        #pragma unroll
        for (int r = 0; r < 16; ++r) O[mb][r] = 0.f;
    float lsum = 0.f;

    const __bf16* Kb  = qkv + (size_t)(b * T) * R3C + C + h * HD;
    const __bf16* Vtb = Vt + (size_t)bh * 64 * T;

    const int ktmax = qbase + 64;

    for (int kt = 0; kt <= ktmax; kt += 64) {
        __syncthreads();
        // stage K tile: Ks[key][hd]
        #pragma unroll
        for (int i = 0; i < 2; ++i) {
            int idx = tid + 256 * i;
            int kr  = idx >> 3;
            int c8  = idx & 7;
            *(uint4*)&Ks[kr][c8 * 8] = *(const uint4*)(Kb + (size_t)(kt + kr) * R3C + c8 * 8);
        }
        // stage V^T tile: VsT[hd][key]
        #pragma unroll
        for (int i = 0; i < 2; ++i) {
            int idx = tid + 256 * i;
            int d   = idx >> 3;
            int k8  = idx & 7;
            *(uint4*)&VsT[d][k8 * 8] = *(const uint4*)(Vtb + (size_t)d * T + kt + k8 * 8);
        }
        __syncthreads();

        // per 32-key sub-block: S^T -> mask -> exp -> packed b64 write to Ps
        #pragma unroll
        for (int sub = 0; sub < 2; ++sub) {
            f32x16 S;
            #pragma unroll
            for (int r = 0; r < 16; ++r) S[r] = 0.f;
            #pragma unroll
            for (int ks = 0; ks < 4; ++ks) {
                bf16x8 kb = *(const bf16x8*)&Ks[sub * 32 + q5][ks * 16 + half * 8];
                S = __builtin_amdgcn_mfma_f32_32x32x16_bf16(kb, Qb[ks], S, 0, 0, 0);
            }
            // causal mask (wave-uniform guard)
            if (kt + sub * 32 + 31 > srow) {
                #pragma unroll
                for (int r = 0; r < 16; ++r) {
                    int key = kt + sub * 32 + (r & 3) + 8 * (r >> 2) + 4 * half;
                    if (key > srow + q5) S[r] = -1e30f;
                }
            }
            // softmax + pack 4 consecutive keys -> b64 write
            #pragma unroll
            for (int a = 0; a < 4; ++a) {
                union { bf16x4 v; uint2 u; } pk;
                #pragma unroll
                for (int bq = 0; bq < 4; ++bq) {
                    float p = exp2f(fmaf(S[4 * a + bq], K1, K2));
                    lsum += p;
                    pk.v[bq] = (__bf16)p;
                }
                *(uint2*)&Ps[w][q5][sub * 32 + 8 * a + 4 * half] = pk.u;
            }
        }

        // O^T += V^T @ P : A = VsT rows, B = Ps rows (same-pattern reads)
        #pragma unroll
        for (int ks2 = 0; ks2 < 4; ++ks2) {
            bf16x8 pa = *(const bf16x8*)&Ps[w][q5][ks2 * 16 + half * 8];
            #pragma unroll
            for (int mb = 0; mb < 2; ++mb) {
                bf16x8 vb = *(const bf16x8*)&VsT[mb * 32 + q5][ks2 * 16 + half * 8];
                O[mb] = __builtin_amdgcn_mfma_f32_32x32x16_bf16(vb, pa, O[mb], 0, 0, 0);
            }
        }
    }

    // L[q] = own-half sum + partner-half sum
    const float inv = 1.f / (lsum + __shfl_xor(lsum, 32));

    // epilogue: lane q5 owns ctx row srow+q5; d = mb*32 + 8a + 4*half + bq
    __bf16* crow = ctx + (size_t)(b * T + srow + q5) * C + h * HD;
    #pragma unroll
    for (int mb = 0; mb < 2; ++mb)
        #pragma unroll
        for (int a = 0; a < 4; ++a) {
            union { bf16x4 v; uint2 u; } pk;
            #pragma unroll
            for (int bq = 0; bq < 4; ++bq)
                pk.v[bq] = (__bf16)(O[mb][4 * a + bq] * inv);
            *(uint2*)(crow + mb * 32 + 8 * a + 4 * half) = pk.u;
        }
}

extern "C" void kernel_launch(void* const* d_in, const int* in_sizes, int n_in,
                              void* d_out, int out_size, void* d_ws, size_t ws_size,
                              hipStream_t stream) {
    constexpr int B = 4, T = 2048, C = 1024;
    constexpr int M = B * T;          // 8192

    const float* x     = (const float*)d_in[0];
    const float* w_qkv = (const float*)d_in[1];
    const float* w_out = (const float*)d_in[2];
    const float* b_out = (const float*)d_in[3];
    float* out = (float*)d_out;

    char* ws = (char*)d_ws;
    __bf16* xb     = (__bf16*)(ws);                      // 16 MB
    __bf16* wqkvT  = (__bf16*)(ws + (16ull << 20));      //  6 MB
    __bf16* woutT  = (__bf16*)(ws + (22ull << 20));      //  2 MB
    __bf16* qkvb   = (__bf16*)(ws + (24ull << 20));      // 48 MB
    __bf16* ctxb   = (__bf16*)(ws + (72ull << 20));      // 16 MB
    __bf16* Vt     = (__bf16*)(ws + (88ull << 20));      // 16 MB

    // 0) casts / transposes
    cast_bf16<<<(M * C / 4 + 255) / 256, 256, 0, stream>>>(x, xb, M * C / 4);
    transpose_cast<<<dim3(3 * C / 32, C / 32), 256, 0, stream>>>(w_qkv, wqkvT, C, 3 * C);
    transpose_cast<<<dim3(C / 32, C / 32), 256, 0, stream>>>(w_out, woutT, C, C);

    // 1) qkv = xb @ wqkvT^T  (bf16 out)
    gemm_bt<__bf16, false><<<dim3(3 * C / 128, M / 128), 256, 0, stream>>>(
        xb, wqkvT, qkvb, nullptr, M, 3 * C, C);

    // 1b) V transpose
    transpose_v<<<dim3(T / 64, B * 16), 256, 0, stream>>>(qkvb, Vt);

    // 2) MFMA flash attention -> ctxb  (128-row Q-tiles, heavy-first)
    flash_attn_mfma<<<dim3(B * 16, T / 128), 256, 0, stream>>>(qkvb, Vt, ctxb);

    // 3) out = ctxb @ woutT^T + b_out (fp32 out)
    gemm_bt<float, true><<<dim3(C / 128, M / 128), 256, 0, stream>>>(
        ctxb, woutT, out, b_out, M, C, C);
}

// Round 9
// 289.775 us; speedup vs baseline: 1.1447x; 1.0002x over previous
//
#include <hip/hip_runtime.h>
#include <cmath>

// ---------------------------------------------------------------------------
// Causal MHA. B=4, T=2048, C=1024, NH=16, HD=64.
//   0) cast x -> bf16; transpose-cast w_qkv, w_out -> bf16 [N,K]
//   1) qkv_bf16 = xb @ wqkvT^T      (m97-style bf16 MFMA GEMM, bf16 out)
//   1b) Vt[b,h][hd][T] = transpose of V
//   2) flash attention: 32x32x16 MFMA, S^T/O^T orientation, causal
//      PAIR-FUSED blocks (heavy Q-tile + light Q-tile share K/V staging)
//   3) out = ctxb @ woutT^T + b_out (bf16 MFMA GEMM, fp32 out)
// NOTE (r6 post-mortem): register prefetch + __launch_bounds__(256,4) caused
// scratch spill (WRITE_SIZE 16->107MB). Do NOT cap VGPRs or hold long-lived
// prefetch registers across the MFMA section in the attention kernel.
// ---------------------------------------------------------------------------

typedef __bf16 bf16x4 __attribute__((ext_vector_type(4)));
typedef __bf16 bf16x8 __attribute__((ext_vector_type(8)));
typedef float  f32x4  __attribute__((ext_vector_type(4)));
typedef float  f32x16 __attribute__((ext_vector_type(16)));

__device__ __forceinline__ void gload_lds16(const __bf16* g, __bf16* l) {
    __builtin_amdgcn_global_load_lds(
        (const __attribute__((address_space(1))) void*)g,
        (__attribute__((address_space(3))) void*)l,
        16, 0, 0);
}

// ---- cast fp32 -> bf16, 4 elems/thread -------------------------------------
__global__ __launch_bounds__(256) void cast_bf16(const float* __restrict__ in,
                                                 __bf16* __restrict__ out, int n4) {
    int i = blockIdx.x * 256 + threadIdx.x;
    if (i >= n4) return;
    float4 f = *(const float4*)(in + (size_t)i * 4);
    bf16x4 o;
    o[0] = (__bf16)f.x; o[1] = (__bf16)f.y; o[2] = (__bf16)f.z; o[3] = (__bf16)f.w;
    *(bf16x4*)(out + (size_t)i * 4) = o;
}

// ---- transpose + cast: W[K,N] fp32 -> WT[N,K] bf16 -------------------------
__global__ __launch_bounds__(256) void transpose_cast(const float* __restrict__ W,
                                                      __bf16* __restrict__ WT,
                                                      int K, int N) {
    __shared__ float tile[32][33];
    const int n0 = blockIdx.x * 32, k0 = blockIdx.y * 32;
    const int tx = threadIdx.x & 31, ty = threadIdx.x >> 5;
    #pragma unroll
    for (int i = 0; i < 4; ++i)
        tile[ty + 8 * i][tx] = W[(size_t)(k0 + ty + 8 * i) * N + n0 + tx];
    __syncthreads();
    #pragma unroll
    for (int i = 0; i < 4; ++i)
        WT[(size_t)(n0 + ty + 8 * i) * K + k0 + tx] = (__bf16)tile[tx][ty + 8 * i];
}

// ---- V transpose: qkv V columns -> Vt[bh][hd=64][T=2048] -------------------
__global__ __launch_bounds__(256) void transpose_v(const __bf16* __restrict__ qkv,
                                                   __bf16* __restrict__ Vt) {
    constexpr int T = 2048, R3C = 3072;
    __shared__ __bf16 tile[64][72];
    const int bh = blockIdx.y;
    const int b  = bh >> 4, h = bh & 15;
    const int kt = blockIdx.x * 64;
    const int tid = threadIdx.x;
    #pragma unroll
    for (int i = 0; i < 2; ++i) {
        int idx = tid + 256 * i;
        int kr  = idx >> 3;
        int c8  = idx & 7;
        *(uint4*)&tile[kr][c8 * 8] =
            *(const uint4*)(qkv + (size_t)(b * T + kt + kr) * R3C + 2048 + h * 64 + c8 * 8);
    }
    __syncthreads();
    #pragma unroll
    for (int i = 0; i < 2; ++i) {
        int idx = tid + 256 * i;
        int d   = idx >> 3;
        int k8  = idx & 7;
        union { __bf16 v[8]; uint4 u; } t;
        #pragma unroll
        for (int j = 0; j < 8; ++j) t.v[j] = tile[k8 * 8 + j][d];
        *(uint4*)(Vt + ((size_t)bh * 64 + d) * T + kt + k8 * 8) = t.u;
    }
}

// ---------------------------------------------------------------------------
// m97-structure bf16 GEMM: C[M,N] = A[M,K] @ BT[N,K]^T (+bias).
// ---------------------------------------------------------------------------
template <typename OutT, bool BIAS>
__global__ __launch_bounds__(256) void gemm_bt(const __bf16* __restrict__ A,
                                               const __bf16* __restrict__ BT,
                                               OutT* __restrict__ Cc,
                                               const float* __restrict__ bias,
                                               int M, int N, int K) {
    __shared__ __bf16 As[128 * 32];
    __shared__ __bf16 Bs[128 * 32];

    const int tid  = threadIdx.x;
    const int lane = tid & 63;
    const int w    = tid >> 6;
    const int wr   = w >> 1, wc = w & 1;
    const int cc   = lane & 15, gg = lane >> 4;
    const int rowBase = blockIdx.y * 128;
    const int colBase = blockIdx.x * 128;

    f32x4 acc[4][4];
    #pragma unroll
    for (int i = 0; i < 4; ++i)
        #pragma unroll
        for (int j = 0; j < 4; ++j) acc[i][j] = f32x4{0.f, 0.f, 0.f, 0.f};

    for (int k0 = 0; k0 < K; k0 += 32) {
        __syncthreads();
        #pragma unroll
        for (int i = 0; i < 2; ++i) {
            int idx = tid + 256 * i;
            int r   = idx >> 2;
            int c4  = idx & 3;
            gload_lds16(A  + (size_t)(rowBase + r) * K + k0 + c4 * 8, &As[idx * 8]);
            gload_lds16(BT + (size_t)(colBase + r) * K + k0 + c4 * 8, &Bs[idx * 8]);
        }
        __syncthreads();

        bf16x8 af[4], bfr[4];
        #pragma unroll
        for (int i = 0; i < 4; ++i)
            af[i] = *(const bf16x8*)&As[(wr * 64 + i * 16 + cc) * 32 + gg * 8];
        #pragma unroll
        for (int j = 0; j < 4; ++j)
            bfr[j] = *(const bf16x8*)&Bs[(wc * 64 + j * 16 + cc) * 32 + gg * 8];
        #pragma unroll
        for (int i = 0; i < 4; ++i)
            #pragma unroll
            for (int j = 0; j < 4; ++j)
                acc[i][j] = __builtin_amdgcn_mfma_f32_16x16x32_bf16(af[i], bfr[j], acc[i][j], 0, 0, 0);
    }

    #pragma unroll
    for (int i = 0; i < 4; ++i)
        #pragma unroll
        for (int j = 0; j < 4; ++j) {
            const int col = colBase + wc * 64 + j * 16 + cc;
            #pragma unroll
            for (int r = 0; r < 4; ++r) {
                const int row = rowBase + wr * 64 + i * 16 + gg * 4 + r;
                float v = acc[i][j][r];
                if (BIAS) v += bias[col];
                Cc[(size_t)row * N + col] = (OutT)v;
            }
        }
}

// ---------------------------------------------------------------------------
// MFMA flash attention v4: 32x32x16 transposed orientation + causal pair
// fusion. Block = 4 waves; grid (bh=64, y=8). Block processes Q-tile
// qtA = 15-y (heavy) and qtB = y (light). B's K-range is a subset of A's, so
// one K-loop stages each K/V tile once and computes both Q-tiles from it.
// Per-block work is uniform (34 tile-computes) -> no causal tail.
// S^T = mfma(K_frag, Q_frag): col = q = lane&31,
//       row = key = (r&3) + 8*(r>>2) + 4*(lane>>5)   [guide m74/m101]
// P-writes: packed ds_write_b64 into Ps[q][key]; O^T = mfma(V^T_frag, P_frag).
// Fixed-max softmax p = exp2(s*0.125*log2e - 16*log2e); L per-lane + one
// shfl_xor(32) at the end.
// ---------------------------------------------------------------------------
__global__ __launch_bounds__(256) void flash_attn_mfma(const __bf16* __restrict__ qkv,
                                                       const __bf16* __restrict__ Vt,
                                                       __bf16* __restrict__ ctx) {
    constexpr int T = 2048, C = 1024, NH = 16, HD = 64;
    constexpr int R3C = 3 * C;
    constexpr float K1 = 0.125f * 1.44269504088896f;   // scale * log2e
    constexpr float K2 = -16.0f * 1.44269504088896f;   // -M0 * log2e

    const int tid  = threadIdx.x;
    const int lane = tid & 63;
    const int w    = tid >> 6;
    const int q5   = lane & 31;                // q-col within wave tile
    const int half = lane >> 5;                // 0/1

    const int bh   = blockIdx.x;               // 0..63
    const int y    = blockIdx.y;               // 0..7
    const int qtA  = 15 - y;                   // heavy tile
    const int qtB  = y;                        // light tile (rides free)
    const int b    = bh >> 4;
    const int h    = bh & 15;
    const int srowA = qtA * 128 + w * 32;
    const int srowB = qtB * 128 + w * 32;
    const int ktmaxA = qtA * 128 + 64;
    const int ktmaxB = qtB * 128 + 64;

    __shared__ __attribute__((aligned(16))) __bf16 Ks [64][72];   // [key][hd]
    __shared__ __attribute__((aligned(16))) __bf16 VsT[64][72];   // [hd][key]
    __shared__ __attribute__((aligned(16))) __bf16 Ps [4][32][72];// per-wave P[q][key]

    // Q as B-fragments for both tiles: B[n=q5][k=ks*16+half*8+j]
    const __bf16* QrowA = qkv + (size_t)(b * T + srowA + q5) * R3C + h * HD;
    const __bf16* QrowB = qkv + (size_t)(b * T + srowB + q5) * R3C + h * HD;
    bf16x8 QbA[4], QbB[4];
    #pragma unroll
    for (int ks = 0; ks < 4; ++ks) {
        QbA[ks] = *(const bf16x8*)(QrowA + ks * 16 + half * 8);
        QbB[ks] = *(const bf16x8*)(QrowB + ks * 16 + half * 8);
    }

    f32x16 OA[2], OB[2];
    #pragma unroll
    for (int mb = 0; mb < 2; ++mb)
        #pragma unroll
        for (int r = 0; r < 16; ++r) { OA[mb][r] = 0.f; OB[mb][r] = 0.f; }
    float lsumA = 0.f, lsumB = 0.f;

    const __bf16* Kb  = qkv + (size_t)(b * T) * R3C + C + h * HD;
    const __bf16* Vtb = Vt + (size_t)bh * 64 * T;

    for (int kt = 0; kt <= ktmaxA; kt += 64) {
        __syncthreads();
        // stage K tile: Ks[key][hd]
        #pragma unroll
        for (int i = 0; i < 2; ++i) {
            int idx = tid + 256 * i;
            int kr  = idx >> 3;
            int c8  = idx & 7;
            *(uint4*)&Ks[kr][c8 * 8] = *(const uint4*)(Kb + (size_t)(kt + kr) * R3C + c8 * 8);
        }
        // stage V^T tile: VsT[hd][key]
        #pragma unroll
        for (int i = 0; i < 2; ++i) {
            int idx = tid + 256 * i;
            int d   = idx >> 3;
            int k8  = idx & 7;
            *(uint4*)&VsT[d][k8 * 8] = *(const uint4*)(Vtb + (size_t)d * T + kt + k8 * 8);
        }
        __syncthreads();

        // ---- tile A compute ----
        #pragma unroll
        for (int sub = 0; sub < 2; ++sub) {
            f32x16 S;
            #pragma unroll
            for (int r = 0; r < 16; ++r) S[r] = 0.f;
            #pragma unroll
            for (int ks = 0; ks < 4; ++ks) {
                bf16x8 kb = *(const bf16x8*)&Ks[sub * 32 + q5][ks * 16 + half * 8];
                S = __builtin_amdgcn_mfma_f32_32x32x16_bf16(kb, QbA[ks], S, 0, 0, 0);
            }
            if (kt + sub * 32 + 31 > srowA) {
                #pragma unroll
                for (int r = 0; r < 16; ++r) {
                    int key = kt + sub * 32 + (r & 3) + 8 * (r >> 2) + 4 * half;
                    if (key > srowA + q5) S[r] = -1e30f;
                }
            }
            #pragma unroll
            for (int a = 0; a < 4; ++a) {
                union { bf16x4 v; uint2 u; } pk;
                #pragma unroll
                for (int bq = 0; bq < 4; ++bq) {
                    float p = exp2f(fmaf(S[4 * a + bq], K1, K2));
                    lsumA += p;
                    pk.v[bq] = (__bf16)p;
                }
                *(uint2*)&Ps[w][q5][sub * 32 + 8 * a + 4 * half] = pk.u;
            }
        }
        #pragma unroll
        for (int ks2 = 0; ks2 < 4; ++ks2) {
            bf16x8 pa = *(const bf16x8*)&Ps[w][q5][ks2 * 16 + half * 8];
            #pragma unroll
            for (int mb = 0; mb < 2; ++mb) {
                bf16x8 vb = *(const bf16x8*)&VsT[mb * 32 + q5][ks2 * 16 + half * 8];
                OA[mb] = __builtin_amdgcn_mfma_f32_32x32x16_bf16(vb, pa, OA[mb], 0, 0, 0);
            }
        }

        // ---- tile B compute (same staged K/V; block-uniform guard) ----
        if (kt <= ktmaxB) {
            #pragma unroll
            for (int sub = 0; sub < 2; ++sub) {
                f32x16 S;
                #pragma unroll
                for (int r = 0; r < 16; ++r) S[r] = 0.f;
                #pragma unroll
                for (int ks = 0; ks < 4; ++ks) {
                    bf16x8 kb = *(const bf16x8*)&Ks[sub * 32 + q5][ks * 16 + half * 8];
                    S = __builtin_amdgcn_mfma_f32_32x32x16_bf16(kb, QbB[ks], S, 0, 0, 0);
                }
                if (kt + sub * 32 + 31 > srowB) {
                    #pragma unroll
                    for (int r = 0; r < 16; ++r) {
                        int key = kt + sub * 32 + (r & 3) + 8 * (r >> 2) + 4 * half;
                        if (key > srowB + q5) S[r] = -1e30f;
                    }
                }
                #pragma unroll
                for (int a = 0; a < 4; ++a) {
                    union { bf16x4 v; uint2 u; } pk;
                    #pragma unroll
                    for (int bq = 0; bq < 4; ++bq) {
                        float p = exp2f(fmaf(S[4 * a + bq], K1, K2));
                        lsumB += p;
                        pk.v[bq] = (__bf16)p;
                    }
                    *(uint2*)&Ps[w][q5][sub * 32 + 8 * a + 4 * half] = pk.u;
                }
            }
            #pragma unroll
            for (int ks2 = 0; ks2 < 4; ++ks2) {
                bf16x8 pa = *(const bf16x8*)&Ps[w][q5][ks2 * 16 + half * 8];
                #pragma unroll
                for (int mb = 0; mb < 2; ++mb) {
                    bf16x8 vb = *(const bf16x8*)&VsT[mb * 32 + q5][ks2 * 16 + half * 8];
                    OB[mb] = __builtin_amdgcn_mfma_f32_32x32x16_bf16(vb, pa, OB[mb], 0, 0, 0);
                }
            }
        }
    }

    const float invA = 1.f / (lsumA + __shfl_xor(lsumA, 32));
    const float invB = 1.f / (lsumB + __shfl_xor(lsumB, 32));

    __bf16* crowA = ctx + (size_t)(b * T + srowA + q5) * C + h * HD;
    __bf16* crowB = ctx + (size_t)(b * T + srowB + q5) * C + h * HD;
    #pragma unroll
    for (int mb = 0; mb < 2; ++mb)
        #pragma unroll
        for (int a = 0; a < 4; ++a) {
            union { bf16x4 v; uint2 u; } pA, pB;
            #pragma unroll
            for (int bq = 0; bq < 4; ++bq) {
                pA.v[bq] = (__bf16)(OA[mb][4 * a + bq] * invA);
                pB.v[bq] = (__bf16)(OB[mb][4 * a + bq] * invB);
            }
            *(uint2*)(crowA + mb * 32 + 8 * a + 4 * half) = pA.u;
            *(uint2*)(crowB + mb * 32 + 8 * a + 4 * half) = pB.u;
        }
}

extern "C" void kernel_launch(void* const* d_in, const int* in_sizes, int n_in,
                              void* d_out, int out_size, void* d_ws, size_t ws_size,
                              hipStream_t stream) {
    constexpr int B = 4, T = 2048, C = 1024;
    constexpr int M = B * T;          // 8192

    const float* x     = (const float*)d_in[0];
    const float* w_qkv = (const float*)d_in[1];
    const float* w_out = (const float*)d_in[2];
    const float* b_out = (const float*)d_in[3];
    float* out = (float*)d_out;

    char* ws = (char*)d_ws;
    __bf16* xb     = (__bf16*)(ws);                      // 16 MB
    __bf16* wqkvT  = (__bf16*)(ws + (16ull << 20));      //  6 MB
    __bf16* woutT  = (__bf16*)(ws + (22ull << 20));      //  2 MB
    __bf16* qkvb   = (__bf16*)(ws + (24ull << 20));      // 48 MB
    __bf16* ctxb   = (__bf16*)(ws + (72ull << 20));      // 16 MB
    __bf16* Vt     = (__bf16*)(ws + (88ull << 20));      // 16 MB

    // 0) casts / transposes
    cast_bf16<<<(M * C / 4 + 255) / 256, 256, 0, stream>>>(x, xb, M * C / 4);
    transpose_cast<<<dim3(3 * C / 32, C / 32), 256, 0, stream>>>(w_qkv, wqkvT, C, 3 * C);
    transpose_cast<<<dim3(C / 32, C / 32), 256, 0, stream>>>(w_out, woutT, C, C);

    // 1) qkv = xb @ wqkvT^T  (bf16 out)
    gemm_bt<__bf16, false><<<dim3(3 * C / 128, M / 128), 256, 0, stream>>>(
        xb, wqkvT, qkvb, nullptr, M, 3 * C, C);

    // 1b) V transpose
    transpose_v<<<dim3(T / 64, B * 16), 256, 0, stream>>>(qkvb, Vt);

    // 2) MFMA flash attention -> ctxb  (pair-fused causal blocks)
    flash_attn_mfma<<<dim3(B * 16, 8), 256, 0, stream>>>(qkvb, Vt, ctxb);

    // 3) out = ctxb @ woutT^T + b_out (fp32 out)
    gemm_bt<float, true><<<dim3(C / 128, M / 128), 256, 0, stream>>>(
        ctxb, woutT, out, b_out, M, C, C);
}